// Round 7
// baseline (360.067 us; speedup 1.0000x reference)
//
#include <hip/hip_runtime.h>
#include <hip/hip_bf16.h>

// Transformer block: B=32 T=512 C=512 H=8 D=64
// Round 11: abandon the 8/4-phase arc (rounds 7-10 all lost to plain 2-phase
// at these short-K shapes). All four GEMMs -> PERSISTENT 2-phase 128^2:
// grid 512 blocks (2/CU exactly), each block runs TPB tiles (QKV 3, FFN1 4,
// proj/FFN2 1) in one flattened pipeline. On a tile's last K-step we issue
// the NEXT tile's k=0 stage, then run the epilogue (reg->global only) before
// the barrier -> next tile's cold-start latency hides under the epilogue;
// all prologues but the first vanish. Inner loop / swizzle / LDS identical
// to the proven round-5 kernel. Attention/LN/transpose unchanged.

#define B_  32
#define T_  512
#define C_  512
#define H_  8
#define D_  64
#define BT  (B_*T_)      // 16384 rows
#define CF  2048         // 4*C

typedef __hip_bfloat16 bf16;
typedef __attribute__((ext_vector_type(8))) short bf16x8;   // 8 bf16 (4 VGPRs)
typedef __attribute__((ext_vector_type(4))) float f32x4;
typedef __attribute__((ext_vector_type(4))) short short4v;

__device__ __forceinline__ float bf2f(bf16 x) { return __bfloat162float(x); }
__device__ __forceinline__ bf16  f2bf(float x){ return __float2bfloat16(x); }
__device__ __forceinline__ short f2bf_bits(float f){
    bf16 h = __float2bfloat16(f);
    return *reinterpret_cast<short*>(&h);
}
__device__ __forceinline__ float bfbits2f(short s){
    unsigned u = ((unsigned)(unsigned short)s) << 16;
    return __uint_as_float(u);
}

#define AS_G __attribute__((address_space(1)))
#define AS_L __attribute__((address_space(3)))

// ---------------- All weight transposes in one launch ------------------------
__global__ __launch_bounds__(256) void transpose_all(const float* __restrict__ wq,
                                                     const float* __restrict__ wk,
                                                     const float* __restrict__ wv,
                                                     const float* __restrict__ wproj,
                                                     const float* __restrict__ w1,
                                                     const float* __restrict__ w2,
                                                     bf16* __restrict__ wt)
{
    const int t = blockIdx.x;
    const float* src; int K, Nn, k0, n0; size_t dstoff;
    if (t < 192) {
        const int which = t / 64, w = t % 64, hh = w >> 3, kt = w & 7;
        src = (which == 0 ? wq : which == 1 ? wk : wv) + (size_t)hh * 512 * 64;
        K = 512; Nn = 64; k0 = kt * 64; n0 = 0;
        dstoff = (size_t)(which * 512 + hh * 64) * 512;
    } else if (t < 256) {
        const int i = t - 192;
        src = wproj; K = 512; Nn = 512; n0 = (i & 7) * 64; k0 = (i >> 3) * 64;
        dstoff = (size_t)1536 * 512;
    } else if (t < 512) {
        const int i = t - 256;
        src = w1; K = 512; Nn = 2048; n0 = (i & 31) * 64; k0 = (i >> 5) * 64;
        dstoff = (size_t)2048 * 512;
    } else {
        const int i = t - 512;
        src = w2; K = 2048; Nn = 512; n0 = (i & 7) * 64; k0 = (i >> 3) * 64;
        dstoff = (size_t)2048 * 512 + (size_t)2048 * 512;
    }

    __shared__ float tl[64][65];
    const int tid = threadIdx.x;
    #pragma unroll
    for (int j = 0; j < 16; ++j) {
        const int e = j * 256 + tid, r = e >> 6, c = e & 63;
        tl[r][c] = src[(size_t)(k0 + r) * Nn + n0 + c];
    }
    __syncthreads();
    #pragma unroll
    for (int j = 0; j < 16; ++j) {
        const int e = j * 256 + tid, n = e >> 6, kk = e & 63;
        wt[dstoff + (size_t)(n0 + n) * K + k0 + kk] = f2bf(tl[kk][n]);
    }
}

// ---------------- LayerNorm: one block per row (C=512), 256 threads ----------
__global__ __launch_bounds__(256) void ln_kernel(const float* __restrict__ x,
                                                 const float* __restrict__ g,
                                                 const float* __restrict__ b,
                                                 bf16* __restrict__ out)
{
    const int row = blockIdx.x;
    const int tid = threadIdx.x;
    const float* xr = x + (size_t)row * C_;
    float v0 = xr[tid], v1 = xr[tid + 256];

    __shared__ float red[4];

    float s = v0 + v1;
    #pragma unroll
    for (int off = 32; off > 0; off >>= 1) s += __shfl_down(s, off, 64);
    if ((tid & 63) == 0) red[tid >> 6] = s;
    __syncthreads();
    const float mean = (red[0] + red[1] + red[2] + red[3]) * (1.0f / C_);
    __syncthreads();

    float d0 = v0 - mean, d1 = v1 - mean;
    float vs = d0 * d0 + d1 * d1;
    #pragma unroll
    for (int off = 32; off > 0; off >>= 1) vs += __shfl_down(vs, off, 64);
    if ((tid & 63) == 0) red[tid >> 6] = vs;
    __syncthreads();
    const float var  = (red[0] + red[1] + red[2] + red[3]) * (1.0f / C_);
    const float rstd = rsqrtf(var + 1e-5f);

    bf16* orow = out + (size_t)row * C_;
    orow[tid]       = f2bf(d0 * rstd * g[tid]       + b[tid]);
    orow[tid + 256] = f2bf(d1 * rstd * g[tid + 256] + b[tid + 256]);
}

// ---------------- Persistent 2-phase 128^2 MFMA GEMM -------------------------
// C[M,N] = A[M,K](bf16) * Bt[N,K](bf16)^T, M = 16384.
// Grid: 512 flat blocks (2/CU), bijective XCD-swizzled; block handles TPB
// tiles: tile(s) = sbid + s*512 in row-major tile space (tm-major).
// Per K-step: issue next stage (next k, or next tile's k=0) -> 32 MFMA ->
// [tile done? epilogue before barrier] -> barrier.
// 16B chunks XOR-8 swizzled (phys = log ^ (row&7)); C^T accumulation
// (mfma(b,a)) except the QKV v-third (normal orientation, t-packed).
template<bool QKV, bool RELU, bool OUT_BF16>
__global__ __launch_bounds__(256, 2) void mfma_gemm(const bf16* __restrict__ A,
                                                    const bf16* __restrict__ Bt,
                                                    const float* __restrict__ bias,
                                                    const float* __restrict__ res,
                                                    void* __restrict__ outp,
                                                    int N, int K, int TPB)
{
    __shared__ __align__(16) bf16 As[2][128 * 64];
    __shared__ __align__(16) bf16 Bs[2][128 * 64];

    const int tid  = threadIdx.x;
    const int wave = tid >> 6, lane = tid & 63;
    const int l16  = lane & 15, quad = lane >> 4;
    const int wm   = wave >> 1, wn = wave & 1;

    const int nwg = gridDim.x;                       // 512
    const int bid = blockIdx.x;
    const int sbid = (bid & 7) * (nwg >> 3) + (bid >> 3);   // bijective XCD swizzle
    const int ntx = N >> 7;                          // tiles along N

    f32x4 acc[4][4];
    #pragma unroll
    for (int i = 0; i < 4; ++i)
        #pragma unroll
        for (int j = 0; j < 4; ++j) acc[i][j] = (f32x4){0.f, 0.f, 0.f, 0.f};

    auto STAGE = [&](int buf, int tm, int tn, int k0) {
        #pragma unroll
        for (int j = 0; j < 4; ++j) {
            const int g = j * 256 + tid;
            const int row = g >> 3, phys = g & 7;
            const int c = phys ^ (row & 7);          // logical 16B chunk
            __builtin_amdgcn_global_load_lds((const AS_G void*)(A  + (size_t)(tm + row) * K + k0 + c * 8),
                                             (AS_L void*)&As[buf][(size_t)g * 8], 16, 0, 0);
            __builtin_amdgcn_global_load_lds((const AS_G void*)(Bt + (size_t)(tn + row) * K + k0 + c * 8),
                                             (AS_L void*)&Bs[buf][(size_t)g * 8], 16, 0, 0);
        }
    };

    auto EPILOGUE = [&](int tm, int tn, bool vblk) {
        if (QKV) {
            bf16* qkv = (bf16*)outp;             // q base; k at +8M elems, v at +16M
            if (!vblk) {
                const int which = tn >> 9;       // 0=q, 1=k
                bf16* dst = qkv + (size_t)which * (8u << 20);
                #pragma unroll
                for (int mf = 0; mf < 4; ++mf) {
                    const int m = tm + wm * 64 + mf * 16 + l16;   // token (C^T: col=m)
                    const int bb = m >> 9, t = m & 511;
                    #pragma unroll
                    for (int nf = 0; nf < 4; ++nf) {
                        const int nb = tn + wn * 64 + nf * 16 + quad * 4;
                        const int hh = (nb >> 6) & 7, dd = nb & 63;
                        short4v pk;
                        #pragma unroll
                        for (int r = 0; r < 4; ++r) pk[r] = f2bf_bits(acc[mf][nf][r]);
                        *(short4v*)&dst[((size_t)(bb * 8 + hh) * 512 + t) * 64 + dd] = pk;
                    }
                }
            } else {
                bf16* dst = qkv + (size_t)2 * (8u << 20);
                #pragma unroll
                for (int mf = 0; mf < 4; ++mf) {
                    const int mb = tm + wm * 64 + mf * 16 + quad * 4;   // token base
                    const int bb = mb >> 9, t = mb & 511;
                    #pragma unroll
                    for (int nf = 0; nf < 4; ++nf) {
                        const int n = tn + wn * 64 + nf * 16 + l16;
                        const int hh = (n >> 6) & 7, dd = n & 63;
                        short4v pk;
                        #pragma unroll
                        for (int r = 0; r < 4; ++r) pk[r] = f2bf_bits(acc[mf][nf][r]);
                        *(short4v*)&dst[((size_t)(bb * 8 + hh) * 64 + dd) * 512 + t] = pk;
                    }
                }
            }
        } else {
            #pragma unroll
            for (int mf = 0; mf < 4; ++mf) {
                const int m = tm + wm * 64 + mf * 16 + l16;             // C^T: col=m
                #pragma unroll
                for (int nf = 0; nf < 4; ++nf) {
                    const int nb = tn + wn * 64 + nf * 16 + quad * 4;   // 4 consecutive n
                    f32x4 a = acc[mf][nf];
                    if (bias) a += *(const f32x4*)&bias[nb];
                    if (RELU) {
                        #pragma unroll
                        for (int r = 0; r < 4; ++r) a[r] = fmaxf(a[r], 0.0f);
                    }
                    if (res)  a += *(const f32x4*)&res[(size_t)m * N + nb];
                    if (OUT_BF16) {
                        short4v pk;
                        #pragma unroll
                        for (int r = 0; r < 4; ++r) pk[r] = f2bf_bits(a[r]);
                        *(short4v*)&((bf16*)outp)[(size_t)m * N + nb] = pk;
                    } else {
                        *(f32x4*)&((float*)outp)[(size_t)m * N + nb] = a;
                    }
                }
            }
        }
        // reset accumulator for the next tile
        #pragma unroll
        for (int i = 0; i < 4; ++i)
            #pragma unroll
            for (int j = 0; j < 4; ++j) acc[i][j] = (f32x4){0.f, 0.f, 0.f, 0.f};
    };

    // Prologue: first tile's first K-step.
    {
        const int t0 = sbid;
        STAGE(0, (t0 / ntx) << 7, (t0 % ntx) << 7, 0);
    }
    __syncthreads();

    int cur = 0;
    for (int s = 0; s < TPB; ++s) {
        const int tile = sbid + s * nwg;
        const int tm = (tile / ntx) << 7, tn = (tile % ntx) << 7;
        const bool vblk = QKV && (tn >= 1024);

        for (int k0 = 0; k0 < K; k0 += 64) {
            const bool lastk = (k0 + 64 >= K);
            if (!lastk) {
                STAGE(cur ^ 1, tm, tn, k0 + 64);
            } else if (s + 1 < TPB) {
                const int nt = sbid + (s + 1) * nwg;
                STAGE(cur ^ 1, (nt / ntx) << 7, (nt % ntx) << 7, 0);
            }

            #pragma unroll
            for (int half = 0; half < 2; ++half) {
                bf16x8 af[4], bfr[4];
                #pragma unroll
                for (int mf = 0; mf < 4; ++mf) {
                    const int r = wm * 64 + mf * 16 + l16;
                    const int p = (half * 4 + quad) ^ (r & 7);
                    af[mf] = *(const bf16x8*)&As[cur][r * 64 + p * 8];
                }
                #pragma unroll
                for (int nf = 0; nf < 4; ++nf) {
                    const int r = wn * 64 + nf * 16 + l16;
                    const int p = (half * 4 + quad) ^ (r & 7);
                    bfr[nf] = *(const bf16x8*)&Bs[cur][r * 64 + p * 8];
                }
                if (vblk) {
                    #pragma unroll
                    for (int mf = 0; mf < 4; ++mf)
                        #pragma unroll
                        for (int nf = 0; nf < 4; ++nf)
                            acc[mf][nf] = __builtin_amdgcn_mfma_f32_16x16x32_bf16(af[mf], bfr[nf], acc[mf][nf], 0, 0, 0);
                } else {
                    #pragma unroll
                    for (int mf = 0; mf < 4; ++mf)
                        #pragma unroll
                        for (int nf = 0; nf < 4; ++nf)
                            acc[mf][nf] = __builtin_amdgcn_mfma_f32_16x16x32_bf16(bfr[nf], af[mf], acc[mf][nf], 0, 0, 0);
                }
            }

            // Tile finished: epilogue BEFORE the barrier, so the next tile's
            // cold-start stage (issued above) lands while we store.
            if (lastk) EPILOGUE(tm, tn, vblk);

            __syncthreads();
            cur ^= 1;
        }
    }
}

// ---------------- Flash attention: qt-paired, dbuf global_load_lds -----------
#define ATTN_TILE(qa, m_i, l_i, Of, qw, qtT)                                          \
  do {                                                                                \
    f32x4 Sf[4];                                                                      \
    _Pragma("unroll")                                                                 \
    for (int kf = 0; kf < 4; ++kf) {                                                  \
        const int row = kf * 16 + l16;                                                \
        bf16x8 b0 = *(const bf16x8*)&Ks[cur][row * 64 + ((quad ^ (row & 7)) * 8)];    \
        bf16x8 b1 = *(const bf16x8*)&Ks[cur][row * 64 + (((4 + quad) ^ (row & 7)) * 8)]; \
        f32x4 z = (f32x4){0.f, 0.f, 0.f, 0.f};                                        \
        z = __builtin_amdgcn_mfma_f32_16x16x32_bf16(qa[0], b0, z, 0, 0, 0);           \
        z = __builtin_amdgcn_mfma_f32_16x16x32_bf16(qa[1], b1, z, 0, 0, 0);           \
        Sf[kf] = z;                                                                   \
    }                                                                                 \
    if (kt == qtT) {                                                                  \
        _Pragma("unroll")                                                             \
        for (int kf = 0; kf < 4; ++kf)                                                \
            _Pragma("unroll")                                                         \
            for (int r = 0; r < 4; ++r)                                               \
                if (kt * 64 + kf * 16 + l16 > (qw) + quad * 4 + r) Sf[kf][r] = -1e30f;\
    }                                                                                 \
    float mnew[4], alpha[4];                                                          \
    _Pragma("unroll")                                                                 \
    for (int r = 0; r < 4; ++r) {                                                     \
        float v = fmaxf(fmaxf(Sf[0][r], Sf[1][r]), fmaxf(Sf[2][r], Sf[3][r]));        \
        v = fmaxf(v, __shfl_xor(v, 1, 64));                                           \
        v = fmaxf(v, __shfl_xor(v, 2, 64));                                           \
        v = fmaxf(v, __shfl_xor(v, 4, 64));                                           \
        v = fmaxf(v, __shfl_xor(v, 8, 64));                                           \
        mnew[r]   = fmaxf(m_i[r], v);                                                 \
        alpha[r]  = __expf(m_i[r] - mnew[r]);                                         \
        m_i[r]    = mnew[r];                                                          \
    }                                                                                 \
    float rs[4] = {0.f, 0.f, 0.f, 0.f};                                               \
    _Pragma("unroll")                                                                 \
    for (int kf = 0; kf < 4; ++kf) {                                                  \
        _Pragma("unroll")                                                             \
        for (int r = 0; r < 4; ++r) {                                                 \
            float p = __expf(Sf[kf][r] - mnew[r]);                                    \
            rs[r] += p;                                                               \
            Pw[wave][quad * 4 + r][kf * 16 + l16] = f2bf(p);                          \
        }                                                                             \
    }                                                                                 \
    _Pragma("unroll")                                                                 \
    for (int r = 0; r < 4; ++r) {                                                     \
        rs[r] += __shfl_xor(rs[r], 1, 64);                                            \
        rs[r] += __shfl_xor(rs[r], 2, 64);                                            \
        rs[r] += __shfl_xor(rs[r], 4, 64);                                            \
        rs[r] += __shfl_xor(rs[r], 8, 64);                                            \
        l_i[r] = l_i[r] * alpha[r] + rs[r];                                           \
    }                                                                                 \
    _Pragma("unroll")                                                                 \
    for (int f = 0; f < 4; ++f)                                                       \
        _Pragma("unroll")                                                             \
        for (int r = 0; r < 4; ++r)                                                   \
            Of[f][r] *= alpha[r];                                                     \
    bf16x8 pa0 = *(const bf16x8*)&Pw[wave][l16][quad * 8];                            \
    bf16x8 pa1 = *(const bf16x8*)&Pw[wave][l16][32 + quad * 8];                       \
    _Pragma("unroll")                                                                 \
    for (int f = 0; f < 4; ++f) {                                                     \
        const int vrow = f * 16 + l16;                                                \
        bf16x8 vb0 = *(const bf16x8*)&Vt[cur][vrow * 64 + ((quad ^ (vrow & 7)) * 8)]; \
        bf16x8 vb1 = *(const bf16x8*)&Vt[cur][vrow * 64 + (((4 + quad) ^ (vrow & 7)) * 8)]; \
        Of[f] = __builtin_amdgcn_mfma_f32_16x16x32_bf16(pa0, vb0, Of[f], 0, 0, 0);    \
        Of[f] = __builtin_amdgcn_mfma_f32_16x16x32_bf16(pa1, vb1, Of[f], 0, 0, 0);    \
    }                                                                                 \
  } while (0)

__global__ __launch_bounds__(256, 2) void attn_kernel(const bf16* __restrict__ q,
                                                      const bf16* __restrict__ kM,
                                                      const bf16* __restrict__ vT,
                                                      bf16* __restrict__ o)
{
    __shared__ __align__(16) bf16 Ks[2][64 * 64];
    __shared__ __align__(16) bf16 Vt[2][64 * 64];
    __shared__ __align__(16) bf16 Pw[4][16][72];

    const int tid  = threadIdx.x;
    const int wave = tid >> 6, lane = tid & 63;
    const int l16  = lane & 15, quad = lane >> 4;

    const int nwg = gridDim.x * gridDim.y;
    int bid = blockIdx.y * gridDim.x + blockIdx.x;
    bid = (bid & 7) * (nwg >> 3) + (bid >> 3);
    const int pair = bid & 3;
    const int bh   = bid >> 2;

    const int qt0 = pair, qt1 = 7 - pair;
    const int qw0 = qt0 * 64 + wave * 16;
    const int qw1 = qt1 * 64 + wave * 16;

    const float scale = 0.04419417382415922f;  // C^-0.5 (reference uses n_embd)
    bf16x8 qa0[2], qa1[2];
    #pragma unroll
    for (int c = 0; c < 2; ++c) {
        bf16x8 t0 = *(const bf16x8*)(q + ((size_t)bh * T_ + qw0 + l16) * 64 + c * 32 + quad * 8);
        bf16x8 t1 = *(const bf16x8*)(q + ((size_t)bh * T_ + qw1 + l16) * 64 + c * 32 + quad * 8);
        #pragma unroll
        for (int j = 0; j < 8; ++j) {
            t0[j] = f2bf_bits(bfbits2f(t0[j]) * scale);
            t1[j] = f2bf_bits(bfbits2f(t1[j]) * scale);
        }
        qa0[c] = t0; qa1[c] = t1;
    }

    float m0[4], l0[4], m1[4], l1[4];
    f32x4 O0[4], O1[4];
    #pragma unroll
    for (int r = 0; r < 4; ++r) { m0[r] = -1e30f; l0[r] = 0.f; m1[r] = -1e30f; l1[r] = 0.f; }
    #pragma unroll
    for (int f = 0; f < 4; ++f) { O0[f] = (f32x4){0.f,0.f,0.f,0.f}; O1[f] = (f32x4){0.f,0.f,0.f,0.f}; }

    auto STAGE = [&](int buf, int kt) {
        const int k0 = kt * 64;
        #pragma unroll
        for (int j = 0; j < 2; ++j) {
            const int g = j * 256 + tid;
            const int row = g >> 3, phys = g & 7;
            const int c = phys ^ (row & 7);
            __builtin_amdgcn_global_load_lds((const AS_G void*)(kM + ((size_t)bh * T_ + k0 + row) * 64 + c * 8),
                                             (AS_L void*)&Ks[buf][(size_t)g * 8], 16, 0, 0);
            __builtin_amdgcn_global_load_lds((const AS_G void*)(vT + ((size_t)bh * 64 + row) * T_ + k0 + c * 8),
                                             (AS_L void*)&Vt[buf][(size_t)g * 8], 16, 0, 0);
        }
    };

    STAGE(0, 0);
    __syncthreads();

    int cur = 0;
    for (int kt = 0; kt <= qt1; ++kt) {
        if (kt < qt1) STAGE(cur ^ 1, kt + 1);

        if (kt <= qt0) ATTN_TILE(qa0, m0, l0, O0, qw0, qt0);
        ATTN_TILE(qa1, m1, l1, O1, qw1, qt1);

        __syncthreads();
        cur ^= 1;
    }

    const int b = bh >> 3, hh = bh & 7;
    #pragma unroll
    for (int r = 0; r < 4; ++r) {
        const float inv0 = 1.0f / l0[r];
        const float inv1 = 1.0f / l1[r];
        const int t0 = qw0 + quad * 4 + r;
        const int t1 = qw1 + quad * 4 + r;
        #pragma unroll
        for (int f = 0; f < 4; ++f) {
            o[((size_t)b * T_ + t0) * C_ + hh * 64 + f * 16 + l16] = f2bf(O0[f][r] * inv0);
            o[((size_t)b * T_ + t1) * C_ + hh * 64 + f * 16 + l16] = f2bf(O1[f][r] * inv1);
        }
    }
}

// -----------------------------------------------------------------------------
extern "C" void kernel_launch(void* const* d_in, const int* in_sizes, int n_in,
                              void* d_out, int out_size, void* d_ws, size_t ws_size,
                              hipStream_t stream)
{
    const float* x     = (const float*)d_in[0];
    const float* wq    = (const float*)d_in[1];
    const float* wk    = (const float*)d_in[2];
    const float* wv    = (const float*)d_in[3];
    const float* wproj = (const float*)d_in[4];
    const float* bproj = (const float*)d_in[5];
    const float* w1    = (const float*)d_in[6];
    const float* b1    = (const float*)d_in[7];
    const float* w2    = (const float*)d_in[8];
    const float* b2    = (const float*)d_in[9];
    const float* ln1g  = (const float*)d_in[10];
    const float* ln1b  = (const float*)d_in[11];
    const float* ln2g  = (const float*)d_in[12];
    const float* ln2b  = (const float*)d_in[13];

    // Workspace:
    //  [0,64M)    h,q,k,v (16 MB each; q/k/v contiguous for merged-QKV scatter)
    //             -> later mid (BT x 2048 bf16)
    //  [64,80M)   o (B,T,C bf16)
    //  [80,96M)   h2 (bf16)
    //  [96,102M)  Wt: qkvt[1536][512] | projt[512][512] | w1t[2048][512] | w2t[512][2048]
    //  x1 (f32) lives in d_out (same-thread RMW in final epilogue)
    char* ws = (char*)d_ws;
    bf16*  h    = (bf16*)(ws + 0);
    bf16*  q    = (bf16*)(ws + ((size_t)16 << 20));
    bf16*  k    = (bf16*)(ws + ((size_t)32 << 20));
    bf16*  v    = (bf16*)(ws + ((size_t)48 << 20));   // (B,H,D,T)
    bf16*  mid  = (bf16*)(ws + 0);
    bf16*  o    = (bf16*)(ws + ((size_t)64 << 20));
    bf16*  h2   = (bf16*)(ws + ((size_t)80 << 20));
    bf16*  wt   = (bf16*)(ws + ((size_t)96 << 20));
    bf16*  projt = wt + (size_t)1536 * 512;
    bf16*  w1t   = wt + (size_t)2048 * 512;
    bf16*  w2t   = wt + (size_t)4096 * 512;
    float* x1    = (float*)d_out;

    // 0. all weight transposes (f32 -> bf16, [N][K])
    transpose_all<<<768, 256, 0, stream>>>(wq, wk, wv, wproj, w1, w2, wt);

    // 1. h = LN1(x)
    ln_kernel<<<BT, 256, 0, stream>>>(x, ln1g, ln1b, h);

    // 2. q|k|v = h @ wqkv  (one N=1536 GEMM); persistent, 1536 tiles / 512 = 3
    mfma_gemm<true,  false, true ><<<512, 256, 0, stream>>>(h, wt, nullptr, nullptr, q, 1536, 512, 3);

    // 3. o = flash-attn(q,k,v) -> (B,T,C); qt-paired grid
    attn_kernel<<<dim3(4, B_ * H_), 256, 0, stream>>>(q, k, v, o);

    // 4. x1 = x + o @ w_proj + b_proj   (x1 = d_out, f32); 512 tiles, TPB 1
    mfma_gemm<false, false, false><<<512, 256, 0, stream>>>(o, projt, bproj, x, x1, 512, 512, 1);

    // 5. h2 = LN2(x1)
    ln_kernel<<<BT, 256, 0, stream>>>(x1, ln2g, ln2b, h2);

    // 6. mid = relu(h2 @ w1 + b1); persistent, 2048 tiles / 512 = 4
    mfma_gemm<false, true,  true ><<<512, 256, 0, stream>>>(h2, w1t, b1, nullptr, mid, 2048, 512, 4);

    // 7. out = x1 + mid @ w2 + b2 (in-place on d_out); 512 tiles, TPB 1
    mfma_gemm<false, false, false><<<512, 256, 0, stream>>>(mid, w2t, b2, x1, (float*)d_out, 512, 2048, 1);
}